// Round 15
// baseline (77.561 us; speedup 1.0000x reference)
//
#include <hip/hip_runtime.h>

// B=131072 points (D=16 fp32), K=256 centers. Out (fp32): [B] argmin idx ++ [B,16] offsets.
//
// Round-15: dim-packed pk_fma fed from LDS (VGPR pairs), REPEAT=1.
// Model from r13 counters (VALUBusy 79%, scan 15.9us, VALU-active 13.0us =>
// ~59 instr/k-iter = 24 ideal + ~32 v_movs): v_pk_fma_f32 from SGPR pairs
// forces splat movs. Fix: read the center row pairs from the LDS copy (cs4,
// already staged for the epilogue) via ds_read_b128 -> aligned VGPR pairs ->
// all-VGPR VOP3P, zero movs. Wave-uniform address => broadcast, conflict-free.
// VALU/iter: 16 pk_fma + 2 hadd + 6 sel = 24 -> scan ~6.5us, kernel ~12us.
// Floor model (fits r5..r14): total ~ 54 + kernel => predict ~64-68us.
//
// Block = 256 thr = 4 waves, 128 pts (2/lane; dim-packed ya/yb). Wave w scans
// centers [64w,64w+64). score = (c2 + sum_even) + sum_odd — same fp32 order
// as r13 (passed absmax 0). Strict < + ascending k/chunk => lowest-k ties
// (jnp.argmin). Epilogue: r11 LDS center gather.

constexpr int Bn = 131072;
constexpr int Kn = 256;
constexpr int Dn = 16;
constexpr int PTS = 128;      // points per block (2 per lane)
constexpr int NW = 4;         // waves per block == K chunks
constexpr int KC = Kn / NW;   // 64 centers per wave

typedef float v2f __attribute__((ext_vector_type(2)));

__global__ __launch_bounds__(256, 8) void kmeans_kernel(
    const float* __restrict__ traj, const float* __restrict__ centers,
    float* __restrict__ out) {
  __shared__ float c2s[Kn];
  __shared__ float4 cs4[Kn][4];     // centers copy: k-loop pair source + epilogue gather
  __shared__ float sbest[NW * PTS];
  __shared__ int sbi[NW * PTS];
  __shared__ int swin[PTS];

  const int t = threadIdx.x;
  const int blk = blockIdx.x;

  // ---- Stage 1: thread t loads center row t, computes c2, stages row in LDS.
  {
    const float4* cp = reinterpret_cast<const float4*>(centers + t * Dn);
    float4 a = cp[0], b = cp[1], c = cp[2], d = cp[3];
    float s = 0.0f;
    s = fmaf(a.x, a.x, s); s = fmaf(a.y, a.y, s);
    s = fmaf(a.z, a.z, s); s = fmaf(a.w, a.w, s);
    s = fmaf(b.x, b.x, s); s = fmaf(b.y, b.y, s);
    s = fmaf(b.z, b.z, s); s = fmaf(b.w, b.w, s);
    s = fmaf(c.x, c.x, s); s = fmaf(c.y, c.y, s);
    s = fmaf(c.z, c.z, s); s = fmaf(c.w, c.w, s);
    s = fmaf(d.x, d.x, s); s = fmaf(d.y, d.y, s);
    s = fmaf(d.z, d.z, s); s = fmaf(d.w, d.w, s);
    c2s[t] = s;
    cs4[t][0] = a; cs4[t][1] = b; cs4[t][2] = c; cs4[t][3] = d;
  }
  __syncthreads();

  const int w = __builtin_amdgcn_readfirstlane(t >> 6);  // wave id (SGPR)
  const int l = t & 63;                                  // lane
  const int p0 = blk * PTS + l;        // this lane's point 0
  const int p1 = p0 + 64;              // this lane's point 1

  // ---- DIM-packed y = -2*x: ya[j] = {x_2j, x_2j+1} of p0, yb likewise p1.
  v2f ya[8], yb[8];
  {
    const v2f* xa = reinterpret_cast<const v2f*>(traj + (size_t)p0 * Dn);
    const v2f* xb = reinterpret_cast<const v2f*>(traj + (size_t)p1 * Dn);
#pragma unroll
    for (int j = 0; j < 8; ++j) {
      v2f a = xa[j], b = xb[j];
      ya[j] = (v2f){-2.0f * a.x, -2.0f * a.y};
      yb[j] = (v2f){-2.0f * b.x, -2.0f * b.y};
    }
  }

  float best0 = __builtin_inff(), best1 = __builtin_inff();
  int bi0 = 0, bi1 = 0;
  const int k0 = w * KC;
#pragma unroll 4
  for (int kk = 0; kk < KC; ++kk) {
    const int k = k0 + kk;
    // Wave-uniform LDS row -> ds_read_b128 -> aligned VGPR pairs (broadcast,
    // conflict-free). All-VGPR v_pk_fma_f32, no splat movs (the r13 bloat).
    const v2f* rp = reinterpret_cast<const v2f*>(&cs4[k][0]);  // 8 pairs
    const float c2k = c2s[k];
    v2f aa = (v2f){c2k, 0.0f};
    v2f ab = (v2f){c2k, 0.0f};
#pragma unroll
    for (int j = 0; j < 8; ++j) {
      const v2f c = rp[j];
      aa = ya[j] * c + aa;             // v_pk_fma_f32 (VGPR,VGPR,VGPR)
      ab = yb[j] * c + ab;
    }
    const float s0 = aa.x + aa.y;      // horizontal: even+odd partials
    const float s1 = ab.x + ab.y;
    if (s0 < best0) { best0 = s0; bi0 = k; }  // strict <: lowest-k ties
    if (s1 < best1) { best1 = s1; bi1 = k; }
  }
  sbest[w * PTS + l] = best0;
  sbi[w * PTS + l] = bi0;
  sbest[w * PTS + 64 + l] = best1;
  sbi[w * PTS + 64 + l] = bi1;
  __syncthreads();

  // ---- Cross-wave reduction: threads 0..127, one per point. Ascending chunk
  // order + strict < keeps the lowest-k winner on exact ties.
  if (t < PTS) {
    float b0 = sbest[t];
    int i0 = sbi[t];
#pragma unroll
    for (int ww = 1; ww < NW; ++ww) {
      float b1 = sbest[ww * PTS + t];
      int i1 = sbi[ww * PTS + t];
      if (b1 < b0) { b0 = b1; i0 = i1; }
    }
    swin[t] = i0;
    out[blk * PTS + t] = (float)i0;  // idx output (fp32 buffer), coalesced
  }
  __syncthreads();

  // ---- Coalesced offset stores: 128 points x 4 quarters = 512 float4 ops.
#pragma unroll
  for (int it = 0; it < 2; ++it) {
    const int id = it * 256 + t;
    const int pb = id >> 2, q = id & 3;
    const int pt = blk * PTS + pb;
    const int win = swin[pb];
    float4 xv = reinterpret_cast<const float4*>(traj + (size_t)pt * Dn)[q];  // L1-hot
    float4 cv = cs4[win][q];                                                 // LDS gather
    float4 o = make_float4(xv.x - cv.x, xv.y - cv.y, xv.z - cv.z, xv.w - cv.w);
    reinterpret_cast<float4*>(out + Bn)[(size_t)pt * 4 + q] = o;
  }
}

extern "C" void kernel_launch(void* const* d_in, const int* in_sizes, int n_in,
                              void* d_out, int out_size, void* d_ws, size_t ws_size,
                              hipStream_t stream) {
  (void)in_sizes; (void)n_in; (void)out_size; (void)d_ws; (void)ws_size;
  const float* traj = (const float*)d_in[0];     // [131072, 16]
  const float* centers = (const float*)d_in[1];  // [256, 16]
  float* out = (float*)d_out;                    // [131072] idx ++ [131072*16] offsets
  kmeans_kernel<<<Bn / PTS, 256, 0, stream>>>(traj, centers, out);
}